// Round 4
// baseline (26898.840 us; speedup 1.0000x reference)
//
#include <hip/hip_runtime.h>

constexpr int N = 20000;
constexpr int E = 320000;
constexpr int Bc = 2;
constexpr int D = 64;
constexpr int L = 25;
constexpr float EPS = 1e-5f;

constexpr int GB = 512;        // mega-kernel grid blocks (co-resident: 2/CU x 256)
constexpr int TPB = 512;       // threads per block
constexpr int EW = 8;          // waves per block
constexpr int NWAVES = GB * EW;
constexpr int TPG = E / 16;    // edge tiles per graph = 20000

typedef __attribute__((ext_vector_type(8))) short short8;
typedef __attribute__((ext_vector_type(4))) float f32x4;

__device__ __forceinline__ unsigned short f2bf(float f) {
  unsigned u = __float_as_uint(f);
  u += 0x7fff + ((u >> 16) & 1);
  return (unsigned short)(u >> 16);
}

__device__ __forceinline__ float wave_sum64(float v) {
#pragma unroll
  for (int off = 32; off > 0; off >>= 1) v += __shfl_xor(v, off, 64);
  return v;
}

// ---------------- CSR build ----------------
__global__ void hist_kernel(const int* __restrict__ row, int* __restrict__ deg) {
  int e = blockIdx.x * blockDim.x + threadIdx.x;
  if (e < E) atomicAdd(&deg[row[e]], 1);
}

__global__ __launch_bounds__(1024) void scan_kernel(const int* __restrict__ deg,
                                                    int* __restrict__ row_start,
                                                    int* __restrict__ cursor) {
  __shared__ int s[1024];
  const int t = threadIdx.x;
  constexpr int CH = (N + 1023) / 1024;
  int base = t * CH;
  int sum = 0;
  for (int k = 0; k < CH; ++k) {
    int idx = base + k;
    if (idx < N) sum += deg[idx];
  }
  s[t] = sum;
  __syncthreads();
  for (int off = 1; off < 1024; off <<= 1) {
    int v = (t >= off) ? s[t - off] : 0;
    __syncthreads();
    s[t] += v;
    __syncthreads();
  }
  int excl = s[t] - sum;
  for (int k = 0; k < CH; ++k) {
    int idx = base + k;
    if (idx < N) {
      row_start[idx] = excl;
      cursor[idx] = excl;
      excl += deg[idx];
    }
  }
  if (t == 1023) row_start[N] = s[1023];
}

__global__ void scatter_kernel(const int* __restrict__ row, int* __restrict__ cursor,
                               int* __restrict__ edge_order) {
  int e = blockIdx.x * blockDim.x + threadIdx.x;
  if (e < E) {
    int p = atomicAdd(&cursor[row[e]], 1);
    edge_order[p] = e;
  }
}

// ---------------- encoder ----------------
__global__ __launch_bounds__(512) void encoder_kernel(
    const float* __restrict__ x, const float* __restrict__ enc_w,
    const float* __restrict__ enc_b, float* __restrict__ h,
    unsigned short* __restrict__ hbf) {
  int idx = blockIdx.x * blockDim.x + threadIdx.x;
  if (idx >= Bc * N * D) return;
  int j = idx & (D - 1);
  int bn = idx >> 6;
  const float* xp = x + (size_t)bn * 3;
  float v = enc_b[j] + xp[0] * enc_w[j] + xp[1] * enc_w[D + j] + xp[2] * enc_w[2 * D + j];
  h[idx] = v;
  hbf[idx] = f2bf(v);
}

// ---------------- grid barrier (all blocks co-resident by construction) ----------------
__device__ __forceinline__ void grid_bar(int* cnt, int* epoch, int ep) {
  __syncthreads();
  if (threadIdx.x == 0) {
    __threadfence();  // flush this block's prior writes (device scope)
    int prev = __hip_atomic_fetch_add(cnt, 1, __ATOMIC_ACQ_REL, __HIP_MEMORY_SCOPE_AGENT);
    if (prev == GB - 1) {
      __hip_atomic_store(cnt, 0, __ATOMIC_RELAXED, __HIP_MEMORY_SCOPE_AGENT);
      __hip_atomic_store(epoch, ep + 1, __ATOMIC_RELEASE, __HIP_MEMORY_SCOPE_AGENT);
    } else {
      while (__hip_atomic_load(epoch, __ATOMIC_ACQUIRE, __HIP_MEMORY_SCOPE_AGENT) < ep + 1) {
        __builtin_amdgcn_s_sleep(2);
      }
    }
    __threadfence();
  }
  __syncthreads();
}

// ---------------- persistent mega-kernel: all 25 layers ----------------
__global__ __launch_bounds__(TPB, 4) void gnn_mega(
    float* __restrict__ h, unsigned short* __restrict__ hbf, float* __restrict__ aggr,
    const int* __restrict__ row, const int* __restrict__ col,
    const float* __restrict__ eattr, const int* __restrict__ edge_order,
    const float* __restrict__ msg_w1, const float* __restrict__ msg_b1,
    const float* __restrict__ msg_ln_g, const float* __restrict__ msg_ln_b,
    const float* __restrict__ msg_w2, const float* __restrict__ msg_b2,
    const float* __restrict__ up_w, const float* __restrict__ up_b,
    const float* __restrict__ up_ln_g, const float* __restrict__ up_ln_b,
    int* __restrict__ bar_cnt, int* __restrict__ bar_epoch) {
  __shared__ __align__(16) char smem[57344];  // 56 KB union

  const int tid = threadIdx.x, lane = tid & 63, w = tid >> 6;
  const int cl = lane & 15, hg = lane >> 4;
  const int wave_global = blockIdx.x * EW + w;
  int ep = 0;

  for (int l = 0; l < L; ++l) {
    // ---------- edge phase ----------
    {
      unsigned short* w1f = (unsigned short*)smem;            // 16 KB
      unsigned short* w2f = (unsigned short*)(smem + 16384);  // 8 KB
      char* pbuf = smem + 24576;                              // 8 x 4 KB

      const float* w1 = msg_w1 + (size_t)l * 130 * 64;
      const float* b1 = msg_b1 + l * 64;
      const float* g1 = msg_ln_g + l * 64;
      const float* be1 = msg_ln_b + l * 64;
      const float* w2 = msg_w2 + (size_t)l * 64 * 64;
      const float* b2 = msg_b2 + l * 64;

      for (int idx = tid; idx < 16 * 512; idx += TPB) {
        int f = idx >> 9, rem = idx & 511, ln = rem >> 3, i = rem & 7;
        int nt = f >> 2, ks = f & 3;
        int k = ks * 32 + (ln >> 4) * 8 + i, n = nt * 16 + (ln & 15);
        w1f[idx] = f2bf(w1[k * 64 + n]);
      }
      for (int idx = tid; idx < 8 * 512; idx += TPB) {
        int f = idx >> 9, rem = idx & 511, ln = rem >> 3, i = rem & 7;
        int nt = f >> 1, ks = f & 1;
        int k = ks * 32 + (ln >> 4) * 8 + i, n = nt * 16 + (ln & 15);
        w2f[idx] = f2bf(w2[k * 64 + n]);
      }
      __syncthreads();

      float b1c[4], g1c[4], be1c[4], b2c[4], wA[4], wB[4];
#pragma unroll
      for (int nt = 0; nt < 4; ++nt) {
        int c = nt * 16 + cl;
        b1c[nt] = b1[c]; g1c[nt] = g1[c]; be1c[nt] = be1[c]; b2c[nt] = b2[c];
        wA[nt] = w1[128 * 64 + c]; wB[nt] = w1[129 * 64 + c];
      }
      const short8* w1v = (const short8*)w1f;
      const short8* w2v = (const short8*)w2f;
      char* pw = pbuf + w * 4096;

      for (int t = wave_global; t < 2 * TPG; t += NWAVES) {
        const int g = (t >= TPG) ? 1 : 0;
        const int tp = t - g * TPG;
        const int pos = tp * 16 + cl;
        const int eid = edge_order[pos];
        const int rv = row[eid], cv = col[eid];
        const float2 ea = *(const float2*)&eattr[2 * (size_t)eid];
        const unsigned short* hb = hbf + (size_t)g * N * 64;

        const unsigned short* pr = hb + ((size_t)rv << 6) + hg * 8;
        const unsigned short* pc = hb + ((size_t)cv << 6) + hg * 8;
        short8 av[4];
        av[0] = *(const short8*)pr;
        av[1] = *(const short8*)(pr + 32);
        av[2] = *(const short8*)pc;
        av[3] = *(const short8*)(pc + 32);

        f32x4 acc[4];
#pragma unroll
        for (int nt = 0; nt < 4; ++nt) acc[nt] = (f32x4){0.f, 0.f, 0.f, 0.f};
#pragma unroll
        for (int ks = 0; ks < 4; ++ks) {
#pragma unroll
          for (int nt = 0; nt < 4; ++nt)
            acc[nt] = __builtin_amdgcn_mfma_f32_16x16x32_bf16(
                av[ks], w1v[(nt * 4 + ks) * 64 + lane], acc[nt], 0, 0, 0);
        }

#pragma unroll
        for (int r = 0; r < 4; ++r) {
          float e0 = __shfl(ea.x, hg * 4 + r, 64);
          float e1 = __shfl(ea.y, hg * 4 + r, 64);
          float v[4];
#pragma unroll
          for (int nt = 0; nt < 4; ++nt)
            v[nt] = acc[nt][r] + b1c[nt] + e0 * wA[nt] + e1 * wB[nt];
          float sum = v[0] + v[1] + v[2] + v[3];
#pragma unroll
          for (int o = 1; o < 16; o <<= 1) sum += __shfl_xor(sum, o, 64);
          float mu = sum * (1.f / 64.f);
          float q = 0.f;
#pragma unroll
          for (int nt = 0; nt < 4; ++nt) { v[nt] -= mu; q += v[nt] * v[nt]; }
#pragma unroll
          for (int o = 1; o < 16; o <<= 1) q += __shfl_xor(q, o, 64);
          float rs = rsqrtf(q * (1.f / 64.f) + EPS);
          const int edge = hg * 4 + r;
#pragma unroll
          for (int nt = 0; nt < 4; ++nt) {
            float p = fmaxf(v[nt] * rs * g1c[nt] + be1c[nt], 0.f);
            unsigned byteoff = (unsigned)(edge * 128 + (nt * 16 + cl) * 2) ^ (unsigned)(hg << 5);
            *(unsigned short*)(pw + byteoff) = f2bf(p);
          }
        }

        f32x4 m[4];
#pragma unroll
        for (int nt = 0; nt < 4; ++nt) m[nt] = (f32x4){0.f, 0.f, 0.f, 0.f};
#pragma unroll
        for (int ks = 0; ks < 2; ++ks) {
          unsigned byteoff = (unsigned)(cl * 128 + (ks * 32 + hg * 8) * 2) ^ (unsigned)((cl >> 2) << 5);
          short8 a2 = *(const short8*)(pw + byteoff);
#pragma unroll
          for (int nt = 0; nt < 4; ++nt)
            m[nt] = __builtin_amdgcn_mfma_f32_16x16x32_bf16(
                a2, w2v[(nt * 2 + ks) * 64 + lane], m[nt], 0, 0, 0);
        }

        float* ms = (float*)pw;
#pragma unroll
        for (int r = 0; r < 4; ++r) {
          const int edge = hg * 4 + r;
          const int swz = ((hg & 3) << 2) ^ ((hg & 1) << 4);
#pragma unroll
          for (int nt = 0; nt < 4; ++nt) {
            int c = nt * 16 + cl;
            ms[edge * 64 + (c ^ swz)] = m[nt][r] + b2c[nt];
          }
        }

        float* ag = aggr + (size_t)g * N * 64;
        float macc = 0.f;
        int rprev = __shfl(rv, 0, 64);
#pragma unroll
        for (int e = 0; e < 16; ++e) {
          int rcur = __shfl(rv, e, 64);
          if (rcur != rprev) {
            atomicAdd(&ag[((size_t)rprev << 6) + lane], macc);
            macc = 0.f;
            rprev = rcur;
          }
          const int eg = e >> 2;
          const int swz = ((eg & 3) << 2) ^ ((eg & 1) << 4);
          macc += ms[e * 64 + (lane ^ swz)];
        }
        atomicAdd(&ag[((size_t)rprev << 6) + lane], macc);
      }
    }
    grid_bar(bar_cnt, bar_epoch, ep); ++ep;

    // ---------- node phase (zeroes aggr after consuming) ----------
    {
      float* wp = (float*)smem;                              // 32 KB
      float (*cat)[4][128] = (float(*)[4][128])(smem + 32768);  // 16 KB

      const float* uw = up_w + (size_t)l * 128 * 64;
      const float* ub = up_b + l * 64;
      const float* ug = up_ln_g + l * 64;
      const float* ube = up_ln_b + l * 64;

      for (int idx = tid; idx < 128 * 64; idx += TPB) {
        int k = idx >> 6, j = idx & 63;
        wp[((k >> 2) << 8) + (j << 2) + (k & 3)] = uw[idx];
      }
      __syncthreads();
      const float ubv = ub[lane], ugv = ug[lane], ubev = ube[lane];
      const int total = Bc * N;
      const int cl4 = (lane & 15) << 2;

      for (int it = 0; it < 3; ++it) {
        const int base = (it * NWAVES + wave_global) * 4;
        int nd = base + hg & 0x7fffffff;  // node this lane-group stages
        nd = base + (lane >> 4);
        if (nd < total) {
          float4 hv = *(const float4*)&h[((size_t)nd << 6) + cl4];
          float4 av = *(const float4*)&aggr[((size_t)nd << 6) + cl4];
          *(float4*)&cat[w][lane >> 4][cl4] = hv;
          *(float4*)&cat[w][lane >> 4][64 + cl4] = av;
          float4 z = {0.f, 0.f, 0.f, 0.f};
          *(float4*)&aggr[((size_t)nd << 6) + cl4] = z;  // pre-zero for next layer
        }
        float t[4];
#pragma unroll
        for (int e = 0; e < 4; ++e) t[e] = ubv;
        for (int k4 = 0; k4 < 32; ++k4) {
          const float4 wv = *(const float4*)&wp[(k4 << 8) + (lane << 2)];
#pragma unroll
          for (int e = 0; e < 4; ++e) {
            const float4 cv = *(const float4*)&cat[w][e][k4 << 2];
            t[e] = fmaf(cv.x, wv.x, t[e]); t[e] = fmaf(cv.y, wv.y, t[e]);
            t[e] = fmaf(cv.z, wv.z, t[e]); t[e] = fmaf(cv.w, wv.w, t[e]);
          }
        }
#pragma unroll
        for (int e = 0; e < 4; ++e) {
          float mu = wave_sum64(t[e]) * (1.f / 64.f);
          float dv = t[e] - mu;
          float var = wave_sum64(dv * dv) * (1.f / 64.f);
          float tn = dv * rsqrtf(var + EPS) * ugv + ubev;
          float u = fmaxf(tn, 0.f);
          int i = base + e;
          if (i < total) {
            float nv = cat[w][e][lane] + u;
            h[((size_t)i << 6) + lane] = nv;
            hbf[((size_t)i << 6) + lane] = f2bf(nv);
          }
        }
      }
    }
    grid_bar(bar_cnt, bar_epoch, ep); ++ep;
  }
}

// ---------------- decoder ----------------
__global__ __launch_bounds__(512) void decoder_kernel(
    const float* __restrict__ h,
    const float* __restrict__ dw1, const float* __restrict__ db1,
    const float* __restrict__ dw2, const float* __restrict__ db2,
    float* __restrict__ out) {
  __shared__ __align__(16) float w1s[64 * 32];
  __shared__ float w2s[64];
  __shared__ float b1s[32];
  __shared__ float hs[8][64];
  const int tid = threadIdx.x;
  const int lane = tid & 63;
  const int w = tid >> 6;

  for (int idx = tid; idx < 64 * 32; idx += 512) w1s[idx] = dw1[idx];
  if (tid < 64) w2s[tid] = dw2[tid];
  if (tid < 32) b1s[tid] = db1[tid];
  const float ob0 = db2[0], ob1 = db2[1];
  __syncthreads();

  const int total = Bc * N;
  const int per_iter = gridDim.x * 8;
  const int niter = (total + per_iter - 1) / per_iter;
  const int wave_global = blockIdx.x * 8 + w;

  for (int it = 0; it < niter; ++it) {
    const int i = it * per_iter + wave_global;
    if (i < total) {
      hs[w][lane] = h[((size_t)i << 6) + lane];
      float s1 = 0.f;
      if (lane < 32) {
        s1 = b1s[lane];
        for (int k = 0; k < 64; ++k) s1 = fmaf(hs[w][k], w1s[k * 32 + lane], s1);
        s1 = fmaxf(s1, 0.f);
      }
      float c0 = (lane < 32) ? s1 * w2s[lane * 2]     : 0.f;
      float c1 = (lane < 32) ? s1 * w2s[lane * 2 + 1] : 0.f;
#pragma unroll
      for (int off = 16; off > 0; off >>= 1) {
        c0 += __shfl_xor(c0, off, 64);
        c1 += __shfl_xor(c1, off, 64);
      }
      if (lane == 0) {
        out[(size_t)i * 2]     = c0 + ob0;
        out[(size_t)i * 2 + 1] = c1 + ob1;
      }
    }
  }
}

extern "C" void kernel_launch(void* const* d_in, const int* in_sizes, int n_in,
                              void* d_out, int out_size, void* d_ws, size_t ws_size,
                              hipStream_t stream) {
  const float* x        = (const float*)d_in[0];
  const int*   ei       = (const int*)d_in[1];
  const float* eattr    = (const float*)d_in[2];
  const float* enc_w    = (const float*)d_in[3];
  const float* enc_b    = (const float*)d_in[4];
  const float* msg_w1   = (const float*)d_in[5];
  const float* msg_b1   = (const float*)d_in[6];
  const float* msg_ln_g = (const float*)d_in[7];
  const float* msg_ln_b = (const float*)d_in[8];
  const float* msg_w2   = (const float*)d_in[9];
  const float* msg_b2   = (const float*)d_in[10];
  const float* up_w     = (const float*)d_in[11];
  const float* up_b     = (const float*)d_in[12];
  const float* up_ln_g  = (const float*)d_in[13];
  const float* up_ln_b  = (const float*)d_in[14];
  const float* dw1      = (const float*)d_in[15];
  const float* db1      = (const float*)d_in[16];
  const float* dw2      = (const float*)d_in[17];
  const float* db2      = (const float*)d_in[18];
  float* out = (float*)d_out;

  float* h            = (float*)d_ws;
  unsigned short* hbf = (unsigned short*)(h + (size_t)Bc * N * D);
  float* aggr         = (float*)(hbf + (size_t)Bc * N * D);
  int* deg        = (int*)(aggr + (size_t)Bc * N * D);
  int* row_start  = deg + N;
  int* cursor     = row_start + N + 1;
  int* edge_order = cursor + N;
  int* bar_cnt    = edge_order + E;
  int* bar_epoch  = bar_cnt + 1;

  const int* row = ei;
  const int* col = ei + E;

  hipMemsetAsync(deg, 0, N * sizeof(int), stream);
  hipMemsetAsync(aggr, 0, (size_t)Bc * N * D * sizeof(float), stream);
  hipMemsetAsync(bar_cnt, 0, 2 * sizeof(int), stream);

  hist_kernel<<<(E + 255) / 256, 256, 0, stream>>>(row, deg);
  scan_kernel<<<1, 1024, 0, stream>>>(deg, row_start, cursor);
  scatter_kernel<<<(E + 255) / 256, 256, 0, stream>>>(row, cursor, edge_order);
  encoder_kernel<<<(Bc * N * D + 511) / 512, 512, 0, stream>>>(x, enc_w, enc_b, h, hbf);

  gnn_mega<<<GB, TPB, 0, stream>>>(
      h, hbf, aggr, row, col, eattr, edge_order,
      msg_w1, msg_b1, msg_ln_g, msg_ln_b, msg_w2, msg_b2,
      up_w, up_b, up_ln_g, up_ln_b, bar_cnt, bar_epoch);

  decoder_kernel<<<512, 512, 0, stream>>>(h, dw1, db1, dw2, db2, out);
}

// Round 5
// 3224.526 us; speedup vs baseline: 8.3420x; 8.3420x over previous
//
#include <hip/hip_runtime.h>

constexpr int N = 20000;
constexpr int E = 320000;
constexpr int Bc = 2;
constexpr int D = 64;
constexpr int L = 25;
constexpr float EPS = 1e-5f;

typedef __attribute__((ext_vector_type(8))) short short8;
typedef __attribute__((ext_vector_type(4))) float f32x4;

__device__ __forceinline__ unsigned short f2bf(float f) {
  unsigned u = __float_as_uint(f);
  u += 0x7fff + ((u >> 16) & 1);   // RNE
  return (unsigned short)(u >> 16);
}

// ---------------- CSR build (once per launch) ----------------
__global__ void hist_kernel(const int* __restrict__ row, int* __restrict__ deg) {
  int e = blockIdx.x * blockDim.x + threadIdx.x;
  if (e < E) atomicAdd(&deg[row[e]], 1);
}

__global__ __launch_bounds__(1024) void scan_kernel(const int* __restrict__ deg,
                                                    int* __restrict__ row_start,
                                                    int* __restrict__ cursor) {
  __shared__ int s[1024];
  const int t = threadIdx.x;
  constexpr int CH = (N + 1023) / 1024;
  int base = t * CH;
  int sum = 0;
  for (int k = 0; k < CH; ++k) {
    int idx = base + k;
    if (idx < N) sum += deg[idx];
  }
  s[t] = sum;
  __syncthreads();
  for (int off = 1; off < 1024; off <<= 1) {
    int v = (t >= off) ? s[t - off] : 0;
    __syncthreads();
    s[t] += v;
    __syncthreads();
  }
  int excl = s[t] - sum;
  for (int k = 0; k < CH; ++k) {
    int idx = base + k;
    if (idx < N) {
      row_start[idx] = excl;
      cursor[idx] = excl;
      excl += deg[idx];
    }
  }
  if (t == 1023) row_start[N] = s[1023];
}

__global__ void scatter_kernel(const int* __restrict__ row, int* __restrict__ cursor,
                               int* __restrict__ edge_order) {
  int e = blockIdx.x * blockDim.x + threadIdx.x;
  if (e < E) {
    int p = atomicAdd(&cursor[row[e]], 1);
    edge_order[p] = e;
  }
}

// ---------------- encoder ----------------
__global__ __launch_bounds__(512) void encoder_kernel(
    const float* __restrict__ x, const float* __restrict__ enc_w,
    const float* __restrict__ enc_b, float* __restrict__ h,
    unsigned short* __restrict__ hbf) {
  int idx = blockIdx.x * blockDim.x + threadIdx.x;
  if (idx >= Bc * N * D) return;
  int j = idx & (D - 1);
  int bn = idx >> 6;
  const float* xp = x + (size_t)bn * 3;
  float v = enc_b[j] + xp[0] * enc_w[j] + xp[1] * enc_w[D + j] + xp[2] * enc_w[2 * D + j];
  h[idx] = v;
  hbf[idx] = f2bf(v);
}

// ---------------- edge kernel: owner-computes, NO atomics, NO memset ----------------
// Each wave owns GPN=8 consecutive nodes of one graph; processes their sorted
// edges in 16-edge MFMA tiles; accumulates per-node sums in private LDS; emits
// plain coalesced stores of aggr (fully overwritten each layer).
constexpr int GPN = 8;              // nodes per group
constexpr int GPG = N / GPN;        // 2500 groups per graph
constexpr int NGRP = GPG * Bc;      // 5000
constexpr int EWB = 4;              // waves per block
constexpr int ETPB = EWB * 64;      // 256

__global__ __launch_bounds__(ETPB) void edge_kernel(
    const unsigned short* __restrict__ hbf, float* __restrict__ aggr,
    const int* __restrict__ row, const int* __restrict__ col,
    const float* __restrict__ eattr,
    const int* __restrict__ row_start, const int* __restrict__ edge_order,
    const float* __restrict__ w1, const float* __restrict__ b1,
    const float* __restrict__ g1, const float* __restrict__ be1,
    const float* __restrict__ w2, const float* __restrict__ b2) {
  __shared__ __align__(16) char smem[49152];  // 48 KB
  unsigned short* w1f = (unsigned short*)smem;            // 16 KB
  unsigned short* w2f = (unsigned short*)(smem + 16384);  // 8 KB

  const int tid = threadIdx.x, lane = tid & 63, w = tid >> 6;
  const int cl = lane & 15, hg = lane >> 4;

  // B-frag staging: frag f; value w[k][n], k=ks*32+(ln>>4)*8+i, n=nt*16+(ln&15)
  for (int idx = tid; idx < 16 * 512; idx += ETPB) {
    int f = idx >> 9, rem = idx & 511, ln = rem >> 3, i = rem & 7;
    int nt = f >> 2, ks = f & 3;
    int k = ks * 32 + (ln >> 4) * 8 + i, n = nt * 16 + (ln & 15);
    w1f[idx] = f2bf(w1[k * 64 + n]);
  }
  for (int idx = tid; idx < 8 * 512; idx += ETPB) {
    int f = idx >> 9, rem = idx & 511, ln = rem >> 3, i = rem & 7;
    int nt = f >> 1, ks = f & 1;
    int k = ks * 32 + (ln >> 4) * 8 + i, n = nt * 16 + (ln & 15);
    w2f[idx] = f2bf(w2[k * 64 + n]);
  }
  __syncthreads();  // only barrier; all below is wave-local

  float b1c[4], g1c[4], be1c[4], b2c[4], wA[4], wB[4];
#pragma unroll
  for (int nt = 0; nt < 4; ++nt) {
    int c = nt * 16 + cl;
    b1c[nt] = b1[c]; g1c[nt] = g1[c]; be1c[nt] = be1[c]; b2c[nt] = b2[c];
    wA[nt] = w1[128 * 64 + c]; wB[nt] = w1[129 * 64 + c];
  }
  const short8* w1v = (const short8*)w1f;
  const short8* w2v = (const short8*)w2f;
  char* pw = smem + 24576 + w * 4096;                 // P (bf16) / ms (f32) staging
  float* aggs = (float*)(smem + 40960 + w * 2048);    // 8 nodes x 64 ch

  const int gw = blockIdx.x * EWB + w;
  if (gw >= NGRP) return;
  const int g = (gw >= GPG) ? 1 : 0;
  const int nb = (gw - g * GPG) * GPN;
  const unsigned short* hb = hbf + (size_t)g * N * 64;
  float* ag = aggr + (size_t)g * N * 64;

#pragma unroll
  for (int k = 0; k < GPN; ++k) aggs[k * 64 + lane] = 0.f;

  const int es = row_start[nb], ee = row_start[nb + GPN];
  int cur = -1;
  float macc = 0.f;

  for (int ts = es; ts < ee; ts += 16) {
    const int valid = min(16, ee - ts);
    int pos = ts + cl;
    if (pos >= ee) pos = ee - 1;        // clamp; masked out of accumulation
    const int eid = edge_order[pos];
    const int rv = row[eid], cv = col[eid];
    const float2 ea = *(const float2*)&eattr[2 * (size_t)eid];

    // A1 gather: lane = (edge cl, k-slice hg)
    const unsigned short* pr = hb + ((size_t)rv << 6) + hg * 8;
    const unsigned short* pc = hb + ((size_t)cv << 6) + hg * 8;
    short8 av[4];
    av[0] = *(const short8*)pr;
    av[1] = *(const short8*)(pr + 32);
    av[2] = *(const short8*)pc;
    av[3] = *(const short8*)(pc + 32);

    f32x4 acc[4];
#pragma unroll
    for (int nt = 0; nt < 4; ++nt) acc[nt] = (f32x4){0.f, 0.f, 0.f, 0.f};
#pragma unroll
    for (int ks = 0; ks < 4; ++ks) {
#pragma unroll
      for (int nt = 0; nt < 4; ++nt)
        acc[nt] = __builtin_amdgcn_mfma_f32_16x16x32_bf16(
            av[ks], w1v[(nt * 4 + ks) * 64 + lane], acc[nt], 0, 0, 0);
    }

    // bias + eattr fold; LN per edge; relu; P -> swizzled LDS (bf16)
#pragma unroll
    for (int r = 0; r < 4; ++r) {
      float e0 = __shfl(ea.x, hg * 4 + r, 64);
      float e1 = __shfl(ea.y, hg * 4 + r, 64);
      float v[4];
#pragma unroll
      for (int nt = 0; nt < 4; ++nt)
        v[nt] = acc[nt][r] + b1c[nt] + e0 * wA[nt] + e1 * wB[nt];
      float sum = v[0] + v[1] + v[2] + v[3];
#pragma unroll
      for (int o = 1; o < 16; o <<= 1) sum += __shfl_xor(sum, o, 64);
      float mu = sum * (1.f / 64.f);
      float q = 0.f;
#pragma unroll
      for (int nt = 0; nt < 4; ++nt) { v[nt] -= mu; q += v[nt] * v[nt]; }
#pragma unroll
      for (int o = 1; o < 16; o <<= 1) q += __shfl_xor(q, o, 64);
      float rs = rsqrtf(q * (1.f / 64.f) + EPS);
      const int edge = hg * 4 + r;
#pragma unroll
      for (int nt = 0; nt < 4; ++nt) {
        float p = fmaxf(v[nt] * rs * g1c[nt] + be1c[nt], 0.f);
        unsigned byteoff = (unsigned)(edge * 128 + (nt * 16 + cl) * 2) ^ (unsigned)(hg << 5);
        *(unsigned short*)(pw + byteoff) = f2bf(p);
      }
    }

    // GEMV2
    f32x4 m[4];
#pragma unroll
    for (int nt = 0; nt < 4; ++nt) m[nt] = (f32x4){0.f, 0.f, 0.f, 0.f};
#pragma unroll
    for (int ks = 0; ks < 2; ++ks) {
      unsigned byteoff = (unsigned)(cl * 128 + (ks * 32 + hg * 8) * 2) ^ (unsigned)((cl >> 2) << 5);
      short8 a2 = *(const short8*)(pw + byteoff);
#pragma unroll
      for (int nt = 0; nt < 4; ++nt)
        m[nt] = __builtin_amdgcn_mfma_f32_16x16x32_bf16(
            a2, w2v[(nt * 2 + ks) * 64 + lane], m[nt], 0, 0, 0);
    }

    // + b2; stage messages f32 [16][64] bank-swizzled
    float* ms = (float*)pw;
#pragma unroll
    for (int r = 0; r < 4; ++r) {
      const int edge = hg * 4 + r;
      const int swz = ((hg & 3) << 2) ^ ((hg & 1) << 4);
#pragma unroll
      for (int nt = 0; nt < 4; ++nt) {
        int c = nt * 16 + cl;
        ms[edge * 64 + (c ^ swz)] = m[nt][r] + b2c[nt];
      }
    }

    // run-accumulate into private LDS (rows sorted; all owned by this wave)
    if (cur < 0) cur = __shfl(rv, 0, 64);
#pragma unroll
    for (int e = 0; e < 16; ++e) {
      if (e < valid) {
        int rcur = __shfl(rv, e, 64);
        if (rcur != cur) {
          aggs[(cur - nb) * 64 + lane] += macc;
          macc = 0.f;
          cur = rcur;
        }
        const int eg = e >> 2;
        const int swz = ((eg & 3) << 2) ^ ((eg & 1) << 4);
        macc += ms[e * 64 + (lane ^ swz)];
      }
    }
  }
  if (cur >= 0) aggs[(cur - nb) * 64 + lane] += macc;

  // plain coalesced stores; zero for degree-0 nodes => aggr needs no memset
#pragma unroll
  for (int k = 0; k < GPN; ++k)
    ag[((size_t)(nb + k) << 6) + lane] = aggs[k * 64 + lane];
}

// ---------------- node kernel: MFMA, 16-node tiles ----------------
constexpr int NT_TOT = Bc * N / 16;   // 2500 tiles
constexpr int NWB = 8;
constexpr int NTPB = 512;

__global__ __launch_bounds__(NTPB) void node_kernel(
    float* __restrict__ h, unsigned short* __restrict__ hbf,
    const float* __restrict__ aggr,
    const float* __restrict__ uw, const float* __restrict__ ub,
    const float* __restrict__ ug, const float* __restrict__ ube) {
  __shared__ __align__(16) unsigned short uwf[16 * 512];  // 16 KB B-frags

  const int tid = threadIdx.x, lane = tid & 63, w = tid >> 6;
  const int cl = lane & 15, hg = lane >> 4;

  for (int idx = tid; idx < 16 * 512; idx += NTPB) {
    int f = idx >> 9, rem = idx & 511, ln = rem >> 3, i = rem & 7;
    int nt = f >> 2, ks = f & 3;
    int k = ks * 32 + (ln >> 4) * 8 + i, n = nt * 16 + (ln & 15);
    uwf[idx] = f2bf(uw[k * 64 + n]);
  }
  __syncthreads();

  const int tt = blockIdx.x * NWB + w;
  if (tt >= NT_TOT) return;

  float ubc[4], ugc[4], ubec[4];
#pragma unroll
  for (int nt = 0; nt < 4; ++nt) {
    int c = nt * 16 + cl;
    ubc[nt] = ub[c]; ugc[nt] = ug[c]; ubec[nt] = ube[c];
  }
  const short8* uwv = (const short8*)uwf;

  constexpr int TPGn = N / 16;  // 1250 tiles per graph
  const int g = (tt >= TPGn) ? 1 : 0;
  const int nbase = (tt - g * TPGn) * 16;
  const size_t gb = (size_t)g * N * 64;

  // A-frags: K = [h(bf16) 0..63 | aggr(f32->bf16) 64..127]; lane = (node cl, slice hg)
  const unsigned short* ph = hbf + gb + (((size_t)(nbase + cl)) << 6) + hg * 8;
  short8 av[4];
  av[0] = *(const short8*)ph;
  av[1] = *(const short8*)(ph + 32);
  const float* pa = aggr + gb + (((size_t)(nbase + cl)) << 6) + hg * 8;
  float4 f0 = *(const float4*)pa;
  float4 f1 = *(const float4*)(pa + 4);
  float4 f2 = *(const float4*)(pa + 32);
  float4 f3 = *(const float4*)(pa + 36);
  {
    union { short8 s; unsigned short u[8]; } t2, t3;
    t2.u[0] = f2bf(f0.x); t2.u[1] = f2bf(f0.y); t2.u[2] = f2bf(f0.z); t2.u[3] = f2bf(f0.w);
    t2.u[4] = f2bf(f1.x); t2.u[5] = f2bf(f1.y); t2.u[6] = f2bf(f1.z); t2.u[7] = f2bf(f1.w);
    t3.u[0] = f2bf(f2.x); t3.u[1] = f2bf(f2.y); t3.u[2] = f2bf(f2.z); t3.u[3] = f2bf(f2.w);
    t3.u[4] = f2bf(f3.x); t3.u[5] = f2bf(f3.y); t3.u[6] = f2bf(f3.z); t3.u[7] = f2bf(f3.w);
    av[2] = t2.s; av[3] = t3.s;
  }

  f32x4 acc[4];
#pragma unroll
  for (int nt = 0; nt < 4; ++nt) acc[nt] = (f32x4){0.f, 0.f, 0.f, 0.f};
#pragma unroll
  for (int ks = 0; ks < 4; ++ks) {
#pragma unroll
    for (int nt = 0; nt < 4; ++nt)
      acc[nt] = __builtin_amdgcn_mfma_f32_16x16x32_bf16(
          av[ks], uwv[(nt * 4 + ks) * 64 + lane], acc[nt], 0, 0, 0);
  }

  // epilogue: bias, LN per node, relu, residual, store h + hbf
#pragma unroll
  for (int r = 0; r < 4; ++r) {
    float v[4];
#pragma unroll
    for (int nt = 0; nt < 4; ++nt) v[nt] = acc[nt][r] + ubc[nt];
    float sum = v[0] + v[1] + v[2] + v[3];
#pragma unroll
    for (int o = 1; o < 16; o <<= 1) sum += __shfl_xor(sum, o, 64);
    float mu = sum * (1.f / 64.f);
    float q = 0.f;
#pragma unroll
    for (int nt = 0; nt < 4; ++nt) { v[nt] -= mu; q += v[nt] * v[nt]; }
#pragma unroll
    for (int o = 1; o < 16; o <<= 1) q += __shfl_xor(q, o, 64);
    float rs = rsqrtf(q * (1.f / 64.f) + EPS);
    const size_t nrow = gb + (((size_t)(nbase + hg * 4 + r)) << 6);
#pragma unroll
    for (int nt = 0; nt < 4; ++nt) {
      int c = nt * 16 + cl;
      float u = fmaxf(v[nt] * rs * ugc[nt] + ubec[nt], 0.f);
      float nv = h[nrow + c] + u;       // quarter-wave 64B coalesced
      h[nrow + c] = nv;
      hbf[nrow + c] = f2bf(nv);
    }
  }
}

// ---------------- decoder ----------------
__global__ __launch_bounds__(512) void decoder_kernel(
    const float* __restrict__ h,
    const float* __restrict__ dw1, const float* __restrict__ db1,
    const float* __restrict__ dw2, const float* __restrict__ db2,
    float* __restrict__ out) {
  __shared__ __align__(16) float w1s[64 * 32];
  __shared__ float w2s[64];
  __shared__ float b1s[32];
  __shared__ float hs[8][64];
  const int tid = threadIdx.x;
  const int lane = tid & 63;
  const int w = tid >> 6;

  for (int idx = tid; idx < 64 * 32; idx += 512) w1s[idx] = dw1[idx];
  if (tid < 64) w2s[tid] = dw2[tid];
  if (tid < 32) b1s[tid] = db1[tid];
  const float ob0 = db2[0], ob1 = db2[1];
  __syncthreads();

  const int total = Bc * N;
  const int per_iter = gridDim.x * 8;
  const int niter = (total + per_iter - 1) / per_iter;
  const int wave_global = blockIdx.x * 8 + w;

  for (int it = 0; it < niter; ++it) {
    const int i = it * per_iter + wave_global;
    if (i < total) {
      hs[w][lane] = h[((size_t)i << 6) + lane];
      float s1 = 0.f;
      if (lane < 32) {
        s1 = b1s[lane];
        for (int k = 0; k < 64; ++k) s1 = fmaf(hs[w][k], w1s[k * 32 + lane], s1);
        s1 = fmaxf(s1, 0.f);
      }
      float c0 = (lane < 32) ? s1 * w2s[lane * 2]     : 0.f;
      float c1 = (lane < 32) ? s1 * w2s[lane * 2 + 1] : 0.f;
#pragma unroll
      for (int off = 16; off > 0; off >>= 1) {
        c0 += __shfl_xor(c0, off, 64);
        c1 += __shfl_xor(c1, off, 64);
      }
      if (lane == 0) {
        out[(size_t)i * 2]     = c0 + ob0;
        out[(size_t)i * 2 + 1] = c1 + ob1;
      }
    }
  }
}

extern "C" void kernel_launch(void* const* d_in, const int* in_sizes, int n_in,
                              void* d_out, int out_size, void* d_ws, size_t ws_size,
                              hipStream_t stream) {
  const float* x        = (const float*)d_in[0];
  const int*   ei       = (const int*)d_in[1];
  const float* eattr    = (const float*)d_in[2];
  const float* enc_w    = (const float*)d_in[3];
  const float* enc_b    = (const float*)d_in[4];
  const float* msg_w1   = (const float*)d_in[5];
  const float* msg_b1   = (const float*)d_in[6];
  const float* msg_ln_g = (const float*)d_in[7];
  const float* msg_ln_b = (const float*)d_in[8];
  const float* msg_w2   = (const float*)d_in[9];
  const float* msg_b2   = (const float*)d_in[10];
  const float* up_w     = (const float*)d_in[11];
  const float* up_b     = (const float*)d_in[12];
  const float* up_ln_g  = (const float*)d_in[13];
  const float* up_ln_b  = (const float*)d_in[14];
  const float* dw1      = (const float*)d_in[15];
  const float* db1      = (const float*)d_in[16];
  const float* dw2      = (const float*)d_in[17];
  const float* db2      = (const float*)d_in[18];
  float* out = (float*)d_out;

  float* h            = (float*)d_ws;
  unsigned short* hbf = (unsigned short*)(h + (size_t)Bc * N * D);
  float* aggr         = (float*)(hbf + (size_t)Bc * N * D);
  int* deg        = (int*)(aggr + (size_t)Bc * N * D);
  int* row_start  = deg + N;
  int* cursor     = row_start + N + 1;
  int* edge_order = cursor + N;

  const int* row = ei;
  const int* col = ei + E;

  hipMemsetAsync(deg, 0, N * sizeof(int), stream);
  hist_kernel<<<(E + 255) / 256, 256, 0, stream>>>(row, deg);
  scan_kernel<<<1, 1024, 0, stream>>>(deg, row_start, cursor);
  scatter_kernel<<<(E + 255) / 256, 256, 0, stream>>>(row, cursor, edge_order);
  encoder_kernel<<<(Bc * N * D + 511) / 512, 512, 0, stream>>>(x, enc_w, enc_b, h, hbf);

  for (int l = 0; l < L; ++l) {
    edge_kernel<<<(NGRP + EWB - 1) / EWB, ETPB, 0, stream>>>(
        hbf, aggr, row, col, eattr, row_start, edge_order,
        msg_w1 + (size_t)l * 130 * 64, msg_b1 + l * 64,
        msg_ln_g + l * 64, msg_ln_b + l * 64,
        msg_w2 + (size_t)l * 64 * 64, msg_b2 + l * 64);
    node_kernel<<<(NT_TOT + NWB - 1) / NWB, NTPB, 0, stream>>>(
        h, hbf, aggr,
        up_w + (size_t)l * 128 * 64, up_b + l * 64,
        up_ln_g + l * 64, up_ln_b + l * 64);
  }

  decoder_kernel<<<512, 512, 0, stream>>>(h, dw1, db1, dw2, db2, out);
}